// Round 3
// baseline (924.133 us; speedup 1.0000x reference)
//
#include <hip/hip_runtime.h>
#include <cstdint>

typedef unsigned short u16;
typedef __attribute__((ext_vector_type(8))) short bf16x8;
typedef __attribute__((ext_vector_type(4))) float f32x4;
typedef __attribute__((ext_vector_type(8))) unsigned short u16x8;
typedef __attribute__((ext_vector_type(4))) unsigned short u16x4;

constexpr int NB = 8;       // batch
constexpr int SEQ = 1024;   // sequence
constexpr int NH = 12;      // heads
constexpr int DM = 768;     // model dim
constexpr int DH = 64;      // head dim

__device__ __forceinline__ u16 f2bf(float f) {
  unsigned int x = __builtin_bit_cast(unsigned int, f);
  x += 0x7fffu + ((x >> 16) & 1u);
  return (u16)(x >> 16);
}

typedef __attribute__((address_space(1))) void* as1vp;
typedef __attribute__((address_space(3))) void* as3vp;

__device__ __forceinline__ void load_lds16(const u16* g, u16* l) {
  __builtin_amdgcn_global_load_lds((as1vp)(g), (as3vp)(l), 16, 0, 0);
}

// C = A @ B. A [M,K] row-major bf16 (lda), B TRANSPOSED: BT [N,K] bf16 (ldb).
// 16x16x32 bf16 MFMA, TM x TN tile, BK=32, 256 threads (2x2 waves).
//  EPI 0: Q/K proj -> bf16 [NB,NH,SEQ,DH] head-split, + fp32 bias
//  EPI 1: V proj   -> bf16 [NB,NH,DH,SEQ] transposed, + fp32 bias
//  EPI 2: scores   -> FP32 attn region, v*0.125 + (1-mask)*-1e4
//  EPI 4: out proj -> FP32 [TOK,DM], + fp32 bias + fp32 residual
template<int TM, int TN, int EPI>
__global__ __launch_bounds__(256)
void gemm_bt(const u16* __restrict__ A, int lda, long long strideA,
             const u16* __restrict__ BT, int ldb, long long strideBT,
             const float* __restrict__ bias,
             const float* __restrict__ extra,
             void* __restrict__ outp,
             int K)
{
  constexpr int BK = 32;
  constexpr int WM = TM / 2, WN = TN / 2;
  constexpr int FM = WM / 16, FN = WN / 16;
  __shared__ u16 As[TM * BK];
  __shared__ u16 Bs[TN * BK];
  const int tid = threadIdx.x;
  const int w = tid >> 6, l = tid & 63;
  const int z = blockIdx.z;
  const u16* Az = A + (long long)z * strideA;
  const u16* Bz = BT + (long long)z * strideBT;
  const int m0 = blockIdx.x * TM, n0 = blockIdx.y * TN;
  const int wm = (w & 1) * WM, wn = (w >> 1) * WN;
  const int quad = l >> 4, md = l & 15;

  f32x4 acc[FM][FN];
  f32x4 zero = {0.f, 0.f, 0.f, 0.f};
  #pragma unroll
  for (int i = 0; i < FM; ++i)
    #pragma unroll
    for (int j = 0; j < FN; ++j) acc[i][j] = zero;

  for (int k0 = 0; k0 < K; k0 += BK) {
    __syncthreads();
    #pragma unroll
    for (int r = 0; r < TM / 64; ++r) {
      int lin = r * 256 + tid;
      int row = lin >> 2, ch = lin & 3;
      load_lds16(Az + (long long)(m0 + row) * lda + k0 + ch * 8, &As[lin * 8]);
    }
    #pragma unroll
    for (int r = 0; r < TN / 64; ++r) {
      int lin = r * 256 + tid;
      int row = lin >> 2, ch = lin & 3;
      load_lds16(Bz + (long long)(n0 + row) * ldb + k0 + ch * 8, &Bs[lin * 8]);
    }
    __syncthreads();
    bf16x8 af[FM], bfr[FN];
    #pragma unroll
    for (int i = 0; i < FM; ++i)
      af[i] = *(const bf16x8*)&As[(wm + i * 16 + md) * BK + quad * 8];
    #pragma unroll
    for (int j = 0; j < FN; ++j)
      bfr[j] = *(const bf16x8*)&Bs[(wn + j * 16 + md) * BK + quad * 8];
    #pragma unroll
    for (int i = 0; i < FM; ++i)
      #pragma unroll
      for (int j = 0; j < FN; ++j)
        acc[i][j] = __builtin_amdgcn_mfma_f32_16x16x32_bf16(af[i], bfr[j], acc[i][j], 0, 0, 0);
  }

  #pragma unroll
  for (int i = 0; i < FM; ++i) {
    #pragma unroll
    for (int j = 0; j < FN; ++j) {
      #pragma unroll
      for (int r = 0; r < 4; ++r) {
        int grow = m0 + wm + i * 16 + quad * 4 + r;
        int gcol = n0 + wn + j * 16 + md;
        float v = acc[i][j][r];
        if constexpr (EPI == 0 || EPI == 1) {
          int b = grow >> 10, s = grow & (SEQ - 1);
          int h = gcol >> 6, dk = gcol & (DH - 1);
          float vb = v + bias[gcol];
          u16* o = (u16*)outp;
          if constexpr (EPI == 0)
            o[(((long long)(b * NH + h)) * SEQ + s) * DH + dk] = f2bf(vb);
          else
            o[(((long long)(b * NH + h)) * DH + dk) * SEQ + s] = f2bf(vb);
        } else if constexpr (EPI == 2) {
          int b = z / NH;
          float mval = extra[b * SEQ + gcol];
          float vv = v * 0.125f + (1.0f - mval) * (-10000.0f);
          ((float*)outp)[((long long)z * SEQ + grow) * SEQ + gcol] = vv;
        } else {
          float vv = v + bias[gcol] + extra[(long long)grow * DM + gcol];
          ((float*)outp)[(long long)grow * DM + gcol] = vv;
        }
      }
    }
  }
}

// ctx GEMM: A is FP32 (attn probs), staged via register cvt -> ds_write.
// BT bf16 via global_load_lds. TM=128, TN=64. Epilogue: merge heads bf16.
__global__ __launch_bounds__(256)
void gemm_ctx(const float* __restrict__ A, const u16* __restrict__ BT,
              u16* __restrict__ outp)
{
  constexpr int TM = 128, TN = 64, BK = 32;
  constexpr int WM = 64, WN = 32, FM = 4, FN = 2;
  __shared__ u16 As[TM * BK];
  __shared__ u16 Bs[TN * BK];
  const int tid = threadIdx.x;
  const int w = tid >> 6, l = tid & 63;
  const int z = blockIdx.z;
  const float* Az = A + (long long)z * SEQ * SEQ;
  const u16* Bz = BT + (long long)z * DH * SEQ;
  const int m0 = blockIdx.x * TM;
  const int wm = (w & 1) * WM, wn = (w >> 1) * WN;
  const int quad = l >> 4, md = l & 15;

  f32x4 acc[FM][FN];
  f32x4 zero = {0.f, 0.f, 0.f, 0.f};
  #pragma unroll
  for (int i = 0; i < FM; ++i)
    #pragma unroll
    for (int j = 0; j < FN; ++j) acc[i][j] = zero;

  for (int k0 = 0; k0 < SEQ; k0 += BK) {
    __syncthreads();
    #pragma unroll
    for (int r = 0; r < 2; ++r) {
      int lin = r * 256 + tid;
      int row = lin >> 2, ch = lin & 3;
      const float* src = Az + (long long)(m0 + row) * SEQ + k0 + ch * 8;
      float4 f0 = *(const float4*)src;
      float4 f1 = *(const float4*)(src + 4);
      u16x8 pk;
      pk[0] = f2bf(f0.x); pk[1] = f2bf(f0.y); pk[2] = f2bf(f0.z); pk[3] = f2bf(f0.w);
      pk[4] = f2bf(f1.x); pk[5] = f2bf(f1.y); pk[6] = f2bf(f1.z); pk[7] = f2bf(f1.w);
      *(u16x8*)&As[lin * 8] = pk;
    }
    {
      int lin = tid;
      int row = lin >> 2, ch = lin & 3;
      load_lds16(Bz + (long long)row * SEQ + k0 + ch * 8, &Bs[lin * 8]);
    }
    __syncthreads();
    bf16x8 af[FM], bfr[FN];
    #pragma unroll
    for (int i = 0; i < FM; ++i)
      af[i] = *(const bf16x8*)&As[(wm + i * 16 + md) * BK + quad * 8];
    #pragma unroll
    for (int j = 0; j < FN; ++j)
      bfr[j] = *(const bf16x8*)&Bs[(wn + j * 16 + md) * BK + quad * 8];
    #pragma unroll
    for (int i = 0; i < FM; ++i)
      #pragma unroll
      for (int j = 0; j < FN; ++j)
        acc[i][j] = __builtin_amdgcn_mfma_f32_16x16x32_bf16(af[i], bfr[j], acc[i][j], 0, 0, 0);
  }

  const int b = z / NH, h = z % NH;
  #pragma unroll
  for (int i = 0; i < FM; ++i) {
    #pragma unroll
    for (int j = 0; j < FN; ++j) {
      #pragma unroll
      for (int r = 0; r < 4; ++r) {
        int grow = m0 + wm + i * 16 + quad * 4 + r;
        int gcol = wn + j * 16 + md;
        outp[(((long long)(b * SEQ + grow)) * DM) + h * DH + gcol] = f2bf(acc[i][j][r]);
      }
    }
  }
}

// in-place fp32 softmax over last dim (1024); one wave per row, 4 rows/block
__global__ __launch_bounds__(256) void softmax_rows(float* __restrict__ attn) {
  const int w = threadIdx.x >> 6, l = threadIdx.x & 63;
  const long long row = (long long)blockIdx.x * 4 + w;
  float* p = attn + row * SEQ;
  float v[16];
  float mx = -3.0e38f;
  #pragma unroll
  for (int c = 0; c < 4; ++c) {
    float4 f = *(const float4*)&p[c * 256 + l * 4];
    v[c*4+0] = f.x; v[c*4+1] = f.y; v[c*4+2] = f.z; v[c*4+3] = f.w;
    mx = fmaxf(mx, fmaxf(fmaxf(f.x, f.y), fmaxf(f.z, f.w)));
  }
  #pragma unroll
  for (int s = 1; s < 64; s <<= 1) mx = fmaxf(mx, __shfl_xor(mx, s, 64));
  float sum = 0.f;
  #pragma unroll
  for (int e = 0; e < 16; ++e) { v[e] = __expf(v[e] - mx); sum += v[e]; }
  #pragma unroll
  for (int s = 1; s < 64; s <<= 1) sum += __shfl_xor(sum, s, 64);
  float inv = 1.0f / sum;
  #pragma unroll
  for (int c = 0; c < 4; ++c) {
    float4 o;
    o.x = v[c*4+0] * inv; o.y = v[c*4+1] * inv;
    o.z = v[c*4+2] * inv; o.w = v[c*4+3] * inv;
    *(float4*)&p[c * 256 + l * 4] = o;
  }
}

// fp32 LayerNorm over 768; one wave per row, 4 rows/block
__global__ __launch_bounds__(256) void layernorm_rows(const float* __restrict__ x,
    const float* __restrict__ gamma, const float* __restrict__ beta,
    float* __restrict__ out) {
  const int w = threadIdx.x >> 6, l = threadIdx.x & 63;
  const long long row = (long long)blockIdx.x * 4 + w;
  const float* px = x + row * DM;
  float v[12];
  float sum = 0.f;
  #pragma unroll
  for (int c = 0; c < 3; ++c) {
    float4 f = *(const float4*)&px[c * 256 + l * 4];
    v[c*4+0] = f.x; v[c*4+1] = f.y; v[c*4+2] = f.z; v[c*4+3] = f.w;
    sum += f.x + f.y + f.z + f.w;
  }
  #pragma unroll
  for (int s = 1; s < 64; s <<= 1) sum += __shfl_xor(sum, s, 64);
  float mu = sum * (1.0f / 768.0f);
  float s2 = 0.f;
  #pragma unroll
  for (int e = 0; e < 12; ++e) { float d = v[e] - mu; s2 += d * d; }
  #pragma unroll
  for (int s = 1; s < 64; s <<= 1) s2 += __shfl_xor(s2, s, 64);
  float rs = rsqrtf(s2 * (1.0f / 768.0f) + 1e-8f);
  #pragma unroll
  for (int c = 0; c < 3; ++c) {
    float4 o;
    #pragma unroll
    for (int e = 0; e < 4; ++e) {
      int col = c * 256 + l * 4 + e;
      ((float*)&o)[e] = (v[c*4+e] - mu) * rs * gamma[col] + beta[col];
    }
    *(float4*)&out[row * DM + c * 256 + l * 4] = o;
  }
}

// cast fp32 [768,768] weights -> bf16 transposed, 4 weights via z
__global__ __launch_bounds__(256) void castT_w(
    const float* __restrict__ W0, const float* __restrict__ W1,
    const float* __restrict__ W2, const float* __restrict__ W3,
    u16* __restrict__ Tbase) {
  __shared__ u16 t[64][65];
  const int z = blockIdx.z;
  const float* W = z == 0 ? W0 : z == 1 ? W1 : z == 2 ? W2 : W3;
  u16* T = Tbase + (long long)z * DM * DM;
  const int bx = blockIdx.x, by = blockIdx.y;
  #pragma unroll
  for (int it = 0; it < 16; ++it) {
    int idx = it * 256 + (int)threadIdx.x;
    int r = idx >> 6, c = idx & 63;
    t[r][c] = f2bf(W[(long long)(by * 64 + r) * DM + bx * 64 + c]);
  }
  __syncthreads();
  #pragma unroll
  for (int it = 0; it < 16; ++it) {
    int idx = it * 256 + (int)threadIdx.x;
    int r = idx >> 6, c = idx & 63;
    T[(long long)(bx * 64 + r) * DM + by * 64 + c] = t[c][r];
  }
}

// cast q/k/v fp32 -> bf16 contiguous, z selects tensor; 8 elems/thread
__global__ __launch_bounds__(256) void cast3_bf16(
    const float* __restrict__ q, const float* __restrict__ k,
    const float* __restrict__ v, u16* __restrict__ dst) {
  const int z = blockIdx.z;
  const float* src = z == 0 ? q : z == 1 ? k : v;
  u16* d = dst + (long long)z * NB * SEQ * DM;
  long long i = ((long long)blockIdx.x * 256 + threadIdx.x) * 8;
  float4 f0 = *(const float4*)&src[i];
  float4 f1 = *(const float4*)&src[i + 4];
  u16x8 o;
  o[0] = f2bf(f0.x); o[1] = f2bf(f0.y); o[2] = f2bf(f0.z); o[3] = f2bf(f0.w);
  o[4] = f2bf(f1.x); o[5] = f2bf(f1.y); o[6] = f2bf(f1.z); o[7] = f2bf(f1.w);
  *(u16x8*)&d[i] = o;
}

extern "C" void kernel_launch(void* const* d_in, const int* in_sizes, int n_in,
                              void* d_out, int out_size, void* d_ws, size_t ws_size,
                              hipStream_t stream) {
  const float* query = (const float*)d_in[0];
  const float* key   = (const float*)d_in[1];
  const float* value = (const float*)d_in[2];
  const float* mask  = (const float*)d_in[3];
  const float* Wq = (const float*)d_in[4];
  const float* bq = (const float*)d_in[5];
  const float* Wk = (const float*)d_in[6];
  const float* bk = (const float*)d_in[7];
  const float* Wv = (const float*)d_in[8];
  const float* bv = (const float*)d_in[9];
  const float* Wo = (const float*)d_in[10];
  const float* bo = (const float*)d_in[11];
  const float* gamma = (const float*)d_in[12];
  const float* beta  = (const float*)d_in[13];

  const long long TOK = (long long)NB * SEQ;        // 8192
  float* out  = (float*)d_out;                      // [TOK, DM] fp32
  float* attn = out + TOK * DM;                     // [NB,NH,SEQ,SEQ] fp32

  // ws: 3 bf16 slots of TOK*DM (37.75 MB total)
  u16* s0 = (u16*)d_ws;            // Qh -> later CTX
  u16* s1 = s0 + TOK * DM;         // Kh -> later X (fp32, spans s1+s2)
  u16* s2 = s1 + TOK * DM;         // VT
  float* X = (float*)s1;           // [TOK, DM] fp32 == s1..s2 exactly

  // scratch in dead d_out regions:
  u16* WqT = (u16*)d_out;          // out region dead until final LN (4.7 MB used)
  u16* WkT = WqT + DM * DM;
  u16* WvT = WkT + DM * DM;
  u16* WoT = WvT + DM * DM;
  u16* qB = (u16*)attn;            // attn region dead until scores GEMM (37.7 MB)
  u16* kB = qB + TOK * DM;
  u16* vB = kB + TOK * DM;

  // 1) weights -> bf16 transposed
  castT_w<<<dim3(12, 12, 4), 256, 0, stream>>>(Wq, Wk, Wv, Wo, WqT);
  // 2) q,k,v -> bf16
  cast3_bf16<<<dim3(3072, 1, 3), 256, 0, stream>>>(query, key, value, qB);

  // 3) QKV projections: M=8192, N=768, K=768
  gemm_bt<128,128,0><<<dim3(64, 6, 1), 256, 0, stream>>>(qB, DM, 0, WqT, DM, 0, bq, nullptr, s0, DM);
  gemm_bt<128,128,0><<<dim3(64, 6, 1), 256, 0, stream>>>(kB, DM, 0, WkT, DM, 0, bk, nullptr, s1, DM);
  gemm_bt<128,128,1><<<dim3(64, 6, 1), 256, 0, stream>>>(vB, DM, 0, WvT, DM, 0, bv, nullptr, s2, DM);

  // 4) scores: per (b,h) M=N=1024, K=64 -> fp32 attn (overwrites qB/kB/vB scratch)
  gemm_bt<128,128,2><<<dim3(8, 8, NB * NH), 256, 0, stream>>>(
      s0, DH, (long long)SEQ * DH, s1, DH, (long long)SEQ * DH, nullptr, mask, attn, DH);

  // 5) softmax in-place (fp32)
  softmax_rows<<<NB * NH * SEQ / 4, 256, 0, stream>>>(attn);

  // 6) ctx: per (b,h) M=1024, N=64, K=1024; A=fp32 attn, B=VT -> CTX bf16 in s0
  gemm_ctx<<<dim3(8, 1, NB * NH), 256, 0, stream>>>(attn, s2, s0);

  // 7) out projection + bias + residual -> X fp32 (s1+s2; Kh,VT dead)
  gemm_bt<128,128,4><<<dim3(64, 6, 1), 256, 0, stream>>>(
      s0, DM, 0, WoT, DM, 0, bo, query, X, DM);

  // 8) LayerNorm -> out (overwrites WqT.. scratch, now dead)
  layernorm_rows<<<(int)(TOK / 4), 256, 0, stream>>>(X, gamma, beta, out);
}